// Round 12
// baseline (143.305 us; speedup 1.0000x reference)
//
#include <hip/hip_runtime.h>
#include <hip/hip_fp16.h>

// Bicubic (Catmull-Rom) warp, faithful to the reference's tile/reshape quirk:
// output plane k uses IMAGE plane k warped with DELTA plane (k % B).
//
// Round-12: the round-10/11 software-pipelined tile strip (T14 async-STAGE
// split) with the REAL spill cause fixed. Rounds 10/11 held the in-flight
// staging values in locals CAPTURED BY REFERENCE in lambdas -> address taken
// -> demoted to scratch (+31..64 MB HBM write traffic, occupancy collapse to
// 36%). This version has no lambdas: the pipeline is straight-line code in
// the t-loop with named float4 locals, so the staging loads live in VGPRs and
// stay in flight across the compute phase.
//
// Structure: each 1024-thread block owns a 64-wide x 128-tall strip =
// 8 tiles of 64x16. Double-buffered fp16 channel-packed halo (2 x 30x82
// cells = 39.4 KB). Per iteration: issue NEXT tile's staging loads + delta
// loads into registers, compute CURRENT tile from LDS (one ds_read_b64 per
// tap), then convert + ds_write the next buffer (vmcnt wait lands there,
// post-compute), barrier. Row clamping is applied unconditionally (gy is the
// only per-tile variable); x-border clamps are hoisted out of the loop.
//
// LDS conflicts (~1.38e7 cyc/dispatch) are the irreducible balls-in-bins
// imbalance of per-lane jittered tap addresses (rounds 5-11: layout no-ops).
//
// Coordinates: xm = x + dx directly (the reference's normalize->unnormalize
// roundtrip is an algebraic identity; fp deviation ~1e-4 px vs 0.1 abs
// threshold). Halo covers |delta| < ~6 (P ~ 2e-9/px); per-lane clamped f32
// global fallback otherwise.

#define TLH 16     // tile height
#define TPB 8      // tiles per block (strip height 128)
#define RTY 7      // top margin (rows above tile top)
#define RWS 30     // halo rows
#define RTX 8      // left margin
#define CLS 80     // halo cols (20 quads)
#define STR 82     // LDS row stride in cells (656 B, 16B-multiple)
#define NQ  (RWS * (CLS / 4))   // 600 staging quads

struct alignas(8) Cell {
    __half2 a;   // (ch0, ch1)
    __half2 b;   // (ch2, 0)
};
struct alignas(16) Cell2 { Cell c0, c1; };

__device__ __forceinline__ void cubic_coeffs(float t, float c[4]) {
    float t2 = t * t;
    float t3 = t2 * t;
    c[0] = (-t3 + 2.0f * t2 - t) * 0.5f;
    c[1] = (3.0f * t3 - 5.0f * t2 + 2.0f) * 0.5f;
    c[2] = (-3.0f * t3 + 4.0f * t2 + t) * 0.5f;
    c[3] = 1.0f - (c[0] + c[1] + c[2]);
}

__global__ __launch_bounds__(1024, 8) void warp_bicubic_kernel(
    const float* __restrict__ img,
    const float* __restrict__ dx,
    const float* __restrict__ dy,
    float* __restrict__ out,
    int B, int C, int H, int W)
{
    __shared__ Cell lds[2][RWS * STR];   // 39360 B -> 2 blocks/CU (wave-capped)

    const int tx = threadIdx.x;              // 0..63
    const int ty = threadIdx.y;              // 0..15
    const int tid = ty * 64 + tx;
    const int X  = blockIdx.x * 64;
    const int Y0 = blockIdx.y * (TLH * TPB);
    const int db = blockIdx.z;
    const int hw = H * W;

    const float* __restrict__ ch0 = img + (size_t)db * hw;
    const float* __restrict__ ch1 = img + (size_t)(db + B) * hw;
    const float* __restrict__ ch2 = img + (size_t)(db + 2 * B) * hw;

    const int x = X + tx;

    // staging geometry (fixed per thread; only gy varies with tile index)
    const bool sact = tid < NQ;
    const int sr   = tid / 20;               // halo row
    const int sqc  = tid - sr * 20;          // quad col
    const int sgx0 = X - RTX + 4 * sqc;      // 16B-aligned when in-bounds
    const bool xfast = (sgx0 >= 0) && (sgx0 <= W - 4);
    const int gxc0 = min(max(sgx0    , 0), W - 1);
    const int gxc1 = min(max(sgx0 + 1, 0), W - 1);
    const int gxc2 = min(max(sgx0 + 2, 0), W - 1);
    const int gxc3 = min(max(sgx0 + 3, 0), W - 1);

    // in-flight staging registers (plain named locals -> VGPRs)
    float4 sv0, sv1, sv2;
    float fdx_n, fdy_n;

    // ---- prologue: issue + write tile 0 ----
    {
        int y0r = Y0 + ty;
        int dofs = db * hw + y0r * W + x;
        fdx_n = dx[dofs];
        fdy_n = dy[dofs];
    }
    if (sact) {
        int gy  = Y0 - RTY + sr;
        int gyc = min(max(gy, 0), H - 1);
        size_t rowb = (size_t)gyc * W;
        if (xfast) {
            sv0 = *(const float4*)(ch0 + rowb + sgx0);
            sv1 = *(const float4*)(ch1 + rowb + sgx0);
            sv2 = *(const float4*)(ch2 + rowb + sgx0);
        } else {
            sv0 = make_float4(ch0[rowb + gxc0], ch0[rowb + gxc1],
                              ch0[rowb + gxc2], ch0[rowb + gxc3]);
            sv1 = make_float4(ch1[rowb + gxc0], ch1[rowb + gxc1],
                              ch1[rowb + gxc2], ch1[rowb + gxc3]);
            sv2 = make_float4(ch2[rowb + gxc0], ch2[rowb + gxc1],
                              ch2[rowb + gxc2], ch2[rowb + gxc3]);
        }
        Cell c0, c1, c2, c3;
        c0.a = __floats2half2_rn(sv0.x, sv1.x); c0.b = __floats2half2_rn(sv2.x, 0.0f);
        c1.a = __floats2half2_rn(sv0.y, sv1.y); c1.b = __floats2half2_rn(sv2.y, 0.0f);
        c2.a = __floats2half2_rn(sv0.z, sv1.z); c2.b = __floats2half2_rn(sv2.z, 0.0f);
        c3.a = __floats2half2_rn(sv0.w, sv1.w); c3.b = __floats2half2_rn(sv2.w, 0.0f);
        Cell2 q0; q0.c0 = c0; q0.c1 = c1;
        Cell2 q1; q1.c0 = c2; q1.c1 = c3;
        Cell2* dst = (Cell2*)&lds[0][sr * STR + 4 * sqc];
        dst[0] = q0;
        dst[1] = q1;
    }
    __syncthreads();

    // ---- pipelined main loop ----
    for (int t = 0; t < TPB; ++t) {
        const float fdx = fdx_n;
        const float fdy = fdy_n;
        const Cell* __restrict__ lbase_buf = lds[t & 1];

        // issue NEXT tile's loads (stay in flight through compute)
        if (t + 1 < TPB) {
            int yn = Y0 + (t + 1) * TLH + ty;
            int dofs = db * hw + yn * W + x;
            fdx_n = dx[dofs];
            fdy_n = dy[dofs];
            if (sact) {
                int gy  = Y0 + (t + 1) * TLH - RTY + sr;
                int gyc = min(max(gy, 0), H - 1);
                size_t rowb = (size_t)gyc * W;
                if (xfast) {
                    sv0 = *(const float4*)(ch0 + rowb + sgx0);
                    sv1 = *(const float4*)(ch1 + rowb + sgx0);
                    sv2 = *(const float4*)(ch2 + rowb + sgx0);
                } else {
                    sv0 = make_float4(ch0[rowb + gxc0], ch0[rowb + gxc1],
                                      ch0[rowb + gxc2], ch0[rowb + gxc3]);
                    sv1 = make_float4(ch1[rowb + gxc0], ch1[rowb + gxc1],
                                      ch1[rowb + gxc2], ch1[rowb + gxc3]);
                    sv2 = make_float4(ch2[rowb + gxc0], ch2[rowb + gxc1],
                                      ch2[rowb + gxc2], ch2[rowb + gxc3]);
                }
            }
        }

        // ---- compute CURRENT tile from LDS ----
        {
            const int Yt = Y0 + t * TLH;
            const int y = Yt + ty;
            const int pos = y * W + x;

            const float xm = (float)x + fdx;
            const float ym = (float)y + fdy;
            const float x0f = floorf(xm);
            const float y0f = floorf(ym);
            const float tfx = xm - x0f;
            const float tfy = ym - y0f;

            float cx[4], cy[4];
            cubic_coeffs(tfx, cx);
            cubic_coeffs(tfy, cy);

            const int x0 = (int)x0f;
            const int y0 = (int)y0f;

            float a0, a1, a2;

            const unsigned ulx = (unsigned)(x0 - X + (RTX - 1));
            const unsigned uly = (unsigned)(y0 - Yt + (RTY - 1));

            if (ulx <= (unsigned)(CLS - 4) && uly <= (unsigned)(RWS - 4)) {
                const Cell* __restrict__ base = lbase_buf + uly * STR + ulx;
                __half2 cxh[4], cyh[4];
#pragma unroll
                for (int j = 0; j < 4; ++j) {
                    cxh[j] = __float2half2_rn(cx[j]);
                    cyh[j] = __float2half2_rn(cy[j]);
                }
                __half2 acc01 = __float2half2_rn(0.0f);
                __half2 acc2  = __float2half2_rn(0.0f);
#pragma unroll
                for (int i = 0; i < 4; ++i) {
                    const Cell* __restrict__ row = base + i * STR;
                    Cell t0 = row[0];
                    Cell t1 = row[1];
                    Cell t2 = row[2];
                    Cell t3 = row[3];
                    __half2 r01 = __hmul2(cxh[0], t0.a);
                    r01 = __hfma2(cxh[1], t1.a, r01);
                    r01 = __hfma2(cxh[2], t2.a, r01);
                    r01 = __hfma2(cxh[3], t3.a, r01);
                    __half2 r2 = __hmul2(cxh[0], t0.b);
                    r2 = __hfma2(cxh[1], t1.b, r2);
                    r2 = __hfma2(cxh[2], t2.b, r2);
                    r2 = __hfma2(cxh[3], t3.b, r2);
                    acc01 = __hfma2(cyh[i], r01, acc01);
                    acc2  = __hfma2(cyh[i], r2, acc2);
                }
                a0 = __low2float(acc01);
                a1 = __high2float(acc01);
                a2 = __low2float(acc2);
            } else {
                // rare tail (|delta| >= ~6): direct clamped f32 global gathers
                a0 = a1 = a2 = 0.0f;
                int xs[4], rowoff[4];
#pragma unroll
                for (int o = 0; o < 4; ++o) {
                    xs[o] = min(max(x0 - 1 + o, 0), W - 1);
                    rowoff[o] = min(max(y0 - 1 + o, 0), H - 1) * W;
                }
#pragma unroll
                for (int i = 0; i < 4; ++i) {
                    float w0 = cy[i] * cx[0], w1 = cy[i] * cx[1];
                    float w2 = cy[i] * cx[2], w3 = cy[i] * cx[3];
                    const float* r0 = ch0 + rowoff[i];
                    const float* r1 = ch1 + rowoff[i];
                    const float* r2 = ch2 + rowoff[i];
                    a0 = fmaf(w0, r0[xs[0]], a0); a0 = fmaf(w1, r0[xs[1]], a0);
                    a0 = fmaf(w2, r0[xs[2]], a0); a0 = fmaf(w3, r0[xs[3]], a0);
                    a1 = fmaf(w0, r1[xs[0]], a1); a1 = fmaf(w1, r1[xs[1]], a1);
                    a1 = fmaf(w2, r1[xs[2]], a1); a1 = fmaf(w3, r1[xs[3]], a1);
                    a2 = fmaf(w0, r2[xs[0]], a2); a2 = fmaf(w1, r2[xs[1]], a2);
                    a2 = fmaf(w2, r2[xs[2]], a2); a2 = fmaf(w3, r2[xs[3]], a2);
                }
            }

            out[(size_t)db * hw + pos] = a0;
            out[(size_t)(db + B) * hw + pos] = a1;
            out[(size_t)(db + 2 * B) * hw + pos] = a2;
        }

        // ---- convert + write NEXT tile's buffer (vmcnt wait lands here) ----
        if (t + 1 < TPB && sact) {
            Cell c0, c1, c2, c3;
            c0.a = __floats2half2_rn(sv0.x, sv1.x); c0.b = __floats2half2_rn(sv2.x, 0.0f);
            c1.a = __floats2half2_rn(sv0.y, sv1.y); c1.b = __floats2half2_rn(sv2.y, 0.0f);
            c2.a = __floats2half2_rn(sv0.z, sv1.z); c2.b = __floats2half2_rn(sv2.z, 0.0f);
            c3.a = __floats2half2_rn(sv0.w, sv1.w); c3.b = __floats2half2_rn(sv2.w, 0.0f);
            Cell2 q0; q0.c0 = c0; q0.c1 = c1;
            Cell2 q1; q1.c0 = c2; q1.c1 = c3;
            Cell2* dst = (Cell2*)&lds[(t + 1) & 1][sr * STR + 4 * sqc];
            dst[0] = q0;
            dst[1] = q1;
        }
        __syncthreads();
    }
}

extern "C" void kernel_launch(void* const* d_in, const int* in_sizes, int n_in,
                              void* d_out, int out_size, void* d_ws, size_t ws_size,
                              hipStream_t stream) {
    const float* img = (const float*)d_in[0];
    const float* dx  = (const float*)d_in[1];
    const float* dy  = (const float*)d_in[2];
    float* out = (float*)d_out;

    const int B = 8, C = 3, H = 1024, W = 1024;
    dim3 block(64, 16, 1);
    dim3 grid(W / 64, H / (TLH * TPB), B);
    warp_bicubic_kernel<<<grid, block, 0, stream>>>(img, dx, dy, out, B, C, H, W);
}

// Round 13
// 87.679 us; speedup vs baseline: 1.6344x; 1.6344x over previous
//
#include <hip/hip_runtime.h>
#include <hip/hip_fp16.h>

// Bicubic (Catmull-Rom) warp, faithful to the reference's tile/reshape quirk:
// output plane k uses IMAGE plane k warped with DELTA plane (k % B).
//
// Round-13: revert to the round-9 structure (single-buffered 64x16 tile,
// 1024 threads, synchronous staging, delta loads hoisted above the barrier)
// -- the register-staged pipeline of rounds 10-12 was unviable (compiler
// demoted in-flight staging regs to scratch, +64..126 MB HBM traffic).
// One change vs round 9: ALL TAP READS ARE 4-BYTE (ds_read_b32).
//   plane A: half2(ch0,ch1) per cell      -> 16 b32 tap reads
//   plane B: half2(ch2[c], ch2[c+1]) DUP  ->  8 b32 tap reads (2/row)
// Rationale (m134 + rounds 5-9 conflict data): b64 taps span 2 banks/lane
// (64 lanes over 16 bank-pairs -> ~10.7 exposed conflict phases/read,
// 171 cyc/wave = the saturated-LDS wall at 63 us). b32 taps are 1 bank/lane
// and ds_read_b32 is ISSUE-limited at ~5.8 cyc -> ~4-5 bank phases hide
// under issue; conflict cost structurally vanishes. 24 b32 ~ 150 cyc/wave
// vs ~300 for 16 b64.
// Plane-B duplication costs one extra scalar ch2 load per staging thread
// (5th element) and 10 KB LDS; taps j={0,1},{2,3} read at cells c, c+2.
//
// Coordinates: xm = x + dx directly (the reference's normalize->unnormalize
// roundtrip is an algebraic identity; fp deviation ~1e-4 px vs 0.1 abs
// threshold). Halo covers |delta| < ~6 (P ~ 2e-9/px); per-lane clamped f32
// global fallback otherwise.

#define RTY 7      // top margin (rows above Y)
#define RWS 30     // halo rows
#define RTX 8      // left margin
#define CLS 80     // halo cols (20 quads)
#define SA  84     // LDS row stride in 4B cells (336 B = 21*16, 16B-multiple)
#define PB  (RWS * SA)          // plane-B offset in cells (2520)
#define NQ  (RWS * (CLS / 4))   // 600 staging quads

__device__ __forceinline__ void cubic_coeffs(float t, float c[4]) {
    float t2 = t * t;
    float t3 = t2 * t;
    c[0] = (-t3 + 2.0f * t2 - t) * 0.5f;
    c[1] = (3.0f * t3 - 5.0f * t2 + 2.0f) * 0.5f;
    c[2] = (-3.0f * t3 + 4.0f * t2 + t) * 0.5f;
    c[3] = 1.0f - (c[0] + c[1] + c[2]);
}

__device__ __forceinline__ unsigned pack2(float a, float b) {
    __half2 h = __floats2half2_rn(a, b);
    return *reinterpret_cast<unsigned*>(&h);
}

__global__ __launch_bounds__(1024, 8) void warp_bicubic_kernel(
    const float* __restrict__ img,
    const float* __restrict__ dx,
    const float* __restrict__ dy,
    float* __restrict__ out,
    int B, int C, int H, int W)
{
    __shared__ unsigned lds[2 * RWS * SA];   // 20160 B

    const int tx = threadIdx.x;              // 0..63
    const int ty = threadIdx.y;              // 0..15
    const int tid = ty * 64 + tx;
    const int X = blockIdx.x * 64;
    const int Y = blockIdx.y * 16;
    const int db = blockIdx.z;
    const int hw = H * W;

    // ---- issue per-pixel delta loads FIRST: latency hides under staging ----
    const int x = X + tx;
    const int y = Y + ty;
    const int pos  = y * W + x;
    const int dofs = db * hw + pos;
    const float fdx = dx[dofs];
    const float fdy = dy[dofs];

    const float* __restrict__ ch0 = img + (size_t)db * hw;
    const float* __restrict__ ch1 = img + (size_t)(db + B) * hw;
    const float* __restrict__ ch2 = img + (size_t)(db + 2 * B) * hw;

    // ---- stage halo: one 4-cell quad per thread (tid < 600) ----
    if (tid < NQ) {
        int r  = tid / 20;                   // halo row
        int qc = tid - r * 20;               // quad col
        int gy  = Y - RTY + r;
        int gyc = min(max(gy, 0), H - 1);
        size_t rowb = (size_t)gyc * W;
        int gx0 = X - RTX + 4 * qc;          // 16B-aligned when in-bounds
        float4 v0, v1, v2;
        float v2e;                           // ch2[gx0+4] for plane-B dup
        if (gx0 >= 0 && gx0 + 4 <= W - 1) {
            v0 = *(const float4*)(ch0 + rowb + gx0);
            v1 = *(const float4*)(ch1 + rowb + gx0);
            v2 = *(const float4*)(ch2 + rowb + gx0);
            v2e = ch2[rowb + gx0 + 4];
        } else {
            int g0 = min(max(gx0    , 0), W - 1);
            int g1 = min(max(gx0 + 1, 0), W - 1);
            int g2 = min(max(gx0 + 2, 0), W - 1);
            int g3 = min(max(gx0 + 3, 0), W - 1);
            int g4 = min(max(gx0 + 4, 0), W - 1);
            v0 = make_float4(ch0[rowb + g0], ch0[rowb + g1], ch0[rowb + g2], ch0[rowb + g3]);
            v1 = make_float4(ch1[rowb + g0], ch1[rowb + g1], ch1[rowb + g2], ch1[rowb + g3]);
            v2 = make_float4(ch2[rowb + g0], ch2[rowb + g1], ch2[rowb + g2], ch2[rowb + g3]);
            v2e = ch2[rowb + g4];
        }
        uint4 ua;                            // plane A: (ch0,ch1) packed
        ua.x = pack2(v0.x, v1.x);
        ua.y = pack2(v0.y, v1.y);
        ua.z = pack2(v0.z, v1.z);
        ua.w = pack2(v0.w, v1.w);
        uint4 ub;                            // plane B: (ch2[c], ch2[c+1])
        ub.x = pack2(v2.x, v2.y);
        ub.y = pack2(v2.y, v2.z);
        ub.z = pack2(v2.z, v2.w);
        ub.w = pack2(v2.w, v2e);
        const int cell = r * SA + 4 * qc;    // byte offset 336r+16qc, 16B-aligned
        *(uint4*)&lds[cell] = ua;
        *(uint4*)&lds[PB + cell] = ub;
    }
    __syncthreads();

    // ---- per-pixel coords & weights (delta already in registers) ----
    const float xm = (float)x + fdx;
    const float ym = (float)y + fdy;
    const float x0f = floorf(xm);
    const float y0f = floorf(ym);
    const float tfx = xm - x0f;
    const float tfy = ym - y0f;

    float cx[4], cy[4];
    cubic_coeffs(tfx, cx);
    cubic_coeffs(tfy, cy);

    const int x0 = (int)x0f;
    const int y0 = (int)y0f;

    float a0, a1, a2;

    // leftmost tap's LDS col = x0-1-(X-RTX) = x0-X+7; need [0, CLS-4]
    const unsigned ulx = (unsigned)(x0 - X + (RTX - 1));
    const unsigned uly = (unsigned)(y0 - Y + (RTY - 1));

    if (ulx <= (unsigned)(CLS - 4) && uly <= (unsigned)(RWS - 4)) {
        const int ib = (int)uly * SA + (int)ulx;
        const __half2* __restrict__ LA = (const __half2*)&lds[ib];
        const __half2* __restrict__ LB = (const __half2*)&lds[PB + ib];

        __half2 cxh[4], cyh[4];
#pragma unroll
        for (int j = 0; j < 4; ++j) {
            cxh[j] = __float2half2_rn(cx[j]);
            cyh[j] = __float2half2_rn(cy[j]);
        }
        // pair weights for plane B: (cx0,cx1) and (cx2,cx3)
        const __half2 pw0 = __halves2half2(__float2half(cx[0]), __float2half(cx[1]));
        const __half2 pw1 = __halves2half2(__float2half(cx[2]), __float2half(cx[3]));

        __half2 acc01 = __float2half2_rn(0.0f);
        __half2 acc2v = __float2half2_rn(0.0f);
#pragma unroll
        for (int i = 0; i < 4; ++i) {
            const __half2* __restrict__ rA = LA + i * SA;
            const __half2* __restrict__ rB = LB + i * SA;
            __half2 a0t = rA[0];
            __half2 a1t = rA[1];
            __half2 a2t = rA[2];
            __half2 a3t = rA[3];
            __half2 r01 = __hmul2(cxh[0], a0t);
            r01 = __hfma2(cxh[1], a1t, r01);
            r01 = __hfma2(cxh[2], a2t, r01);
            r01 = __hfma2(cxh[3], a3t, r01);
            acc01 = __hfma2(cyh[i], r01, acc01);

            __half2 b0t = rB[0];     // (t0, t1)
            __half2 b1t = rB[2];     // (t2, t3)
            __half2 r2 = __hmul2(pw0, b0t);
            r2 = __hfma2(pw1, b1t, r2);
            acc2v = __hfma2(cyh[i], r2, acc2v);
        }
        a0 = __low2float(acc01);
        a1 = __high2float(acc01);
        a2 = __low2float(acc2v) + __high2float(acc2v);
    } else {
        // rare tail (|delta| >= ~6): direct clamped f32 global gathers
        a0 = a1 = a2 = 0.0f;
        int xs[4], rowoff[4];
#pragma unroll
        for (int o = 0; o < 4; ++o) {
            xs[o] = min(max(x0 - 1 + o, 0), W - 1);
            rowoff[o] = min(max(y0 - 1 + o, 0), H - 1) * W;
        }
#pragma unroll
        for (int i = 0; i < 4; ++i) {
            float w0 = cy[i] * cx[0], w1 = cy[i] * cx[1];
            float w2 = cy[i] * cx[2], w3 = cy[i] * cx[3];
            const float* r0 = ch0 + rowoff[i];
            const float* r1 = ch1 + rowoff[i];
            const float* r2 = ch2 + rowoff[i];
            a0 = fmaf(w0, r0[xs[0]], a0); a0 = fmaf(w1, r0[xs[1]], a0);
            a0 = fmaf(w2, r0[xs[2]], a0); a0 = fmaf(w3, r0[xs[3]], a0);
            a1 = fmaf(w0, r1[xs[0]], a1); a1 = fmaf(w1, r1[xs[1]], a1);
            a1 = fmaf(w2, r1[xs[2]], a1); a1 = fmaf(w3, r1[xs[3]], a1);
            a2 = fmaf(w0, r2[xs[0]], a2); a2 = fmaf(w1, r2[xs[1]], a2);
            a2 = fmaf(w2, r2[xs[2]], a2); a2 = fmaf(w3, r2[xs[3]], a2);
        }
    }

    out[(size_t)db * hw + pos] = a0;
    out[(size_t)(db + B) * hw + pos] = a1;
    out[(size_t)(db + 2 * B) * hw + pos] = a2;
}

extern "C" void kernel_launch(void* const* d_in, const int* in_sizes, int n_in,
                              void* d_out, int out_size, void* d_ws, size_t ws_size,
                              hipStream_t stream) {
    const float* img = (const float*)d_in[0];
    const float* dx  = (const float*)d_in[1];
    const float* dy  = (const float*)d_in[2];
    float* out = (float*)d_out;

    const int B = 8, C = 3, H = 1024, W = 1024;
    dim3 block(64, 16, 1);
    dim3 grid(W / 64, H / 16, B);
    warp_bicubic_kernel<<<grid, block, 0, stream>>>(img, dx, dy, out, B, C, H, W);
}

// Round 14
// 70.030 us; speedup vs baseline: 2.0463x; 1.2520x over previous
//
#include <hip/hip_runtime.h>
#include <hip/hip_fp16.h>

// Bicubic (Catmull-Rom) warp, faithful to the reference's tile/reshape quirk:
// output plane k uses IMAGE plane k warped with DELTA plane (k % B).
//
// Round-14: round-9 structure (single-buffered fp16 channel-packed halo,
// one ds_read_b64 per tap, delta loads hoisted above the barrier) with a
// 64x32 output tile and TWO pixels per thread (y rows ty and ty+16).
// Halo amortization: 46x80 = 3680 cells per 2048 px -> 1.80 cells/px vs
// 2.34 at 64x16 (-23% staging VMEM/pack/ds_write per pixel), and barrier
// count per pixel halves. Tap path untouched (r13's read-width change and
// r10-12's register pipeline both regressed and are abandoned).
// Per-pixel state is in #pragma unroll p-loops with static indices only --
// no lambdas, no runtime-indexed arrays (the r10-12 scratch-spill lesson).
//
// LDS conflicts (~1.38e7 cyc/dispatch) are the irreducible balls-in-bins
// imbalance of per-lane jittered tap addresses (rounds 5-13: stride, width,
// and layout changes were all neutral-to-negative).
//
// Coordinates: xm = x + dx directly (the reference's normalize->unnormalize
// roundtrip is an algebraic identity; fp deviation ~1e-4 px vs 0.1 abs
// threshold). Halo covers |delta| < ~6 (P ~ 2e-9/px); per-lane clamped f32
// global fallback otherwise.

#define RTY 7      // top margin (rows above Y)
#define RWS 46     // halo rows (tile height 32 + 14)
#define RTX 8      // left margin
#define CLS 80     // halo cols (20 quads)
#define STR 82     // LDS row stride in cells (656 B = 41*16, 16B-multiple)
#define NQ  (RWS * (CLS / 4))   // 920 staging quads

struct alignas(8) Cell {
    __half2 a;   // (ch0, ch1)
    __half2 b;   // (ch2, 0)
};
struct alignas(16) Cell2 { Cell c0, c1; };

__device__ __forceinline__ void cubic_coeffs(float t, float c[4]) {
    float t2 = t * t;
    float t3 = t2 * t;
    c[0] = (-t3 + 2.0f * t2 - t) * 0.5f;
    c[1] = (3.0f * t3 - 5.0f * t2 + 2.0f) * 0.5f;
    c[2] = (-3.0f * t3 + 4.0f * t2 + t) * 0.5f;
    c[3] = 1.0f - (c[0] + c[1] + c[2]);
}

__global__ __launch_bounds__(1024, 8) void warp_bicubic_kernel(
    const float* __restrict__ img,
    const float* __restrict__ dx,
    const float* __restrict__ dy,
    float* __restrict__ out,
    int B, int C, int H, int W)
{
    __shared__ Cell lds[RWS * STR];   // 30176 B -> 2 blocks/CU (wave-capped)

    const int tx = threadIdx.x;              // 0..63
    const int ty = threadIdx.y;              // 0..15
    const int tid = ty * 64 + tx;
    const int X = blockIdx.x * 64;
    const int Y = blockIdx.y * 32;
    const int db = blockIdx.z;
    const int hw = H * W;

    const int x = X + tx;

    // ---- issue BOTH pixels' delta loads FIRST (hide under staging) ----
    float fdxs[2], fdys[2];
#pragma unroll
    for (int p = 0; p < 2; ++p) {
        int yy = Y + ty + p * 16;
        int dofs = db * hw + yy * W + x;
        fdxs[p] = dx[dofs];
        fdys[p] = dy[dofs];
    }

    const float* __restrict__ ch0 = img + (size_t)db * hw;
    const float* __restrict__ ch1 = img + (size_t)(db + B) * hw;
    const float* __restrict__ ch2 = img + (size_t)(db + 2 * B) * hw;

    // ---- stage halo: one 4-cell quad per thread (tid < 920) ----
    if (tid < NQ) {
        int r  = tid / 20;                   // halo row
        int qc = tid - r * 20;               // quad col
        int gy  = Y - RTY + r;
        int gyc = min(max(gy, 0), H - 1);
        size_t rowb = (size_t)gyc * W;
        int gx0 = X - RTX + 4 * qc;          // 16B-aligned when in-bounds
        float4 v0, v1, v2;
        if (gx0 >= 0 && gx0 <= W - 4) {
            v0 = *(const float4*)(ch0 + rowb + gx0);
            v1 = *(const float4*)(ch1 + rowb + gx0);
            v2 = *(const float4*)(ch2 + rowb + gx0);
        } else {
            int g0 = min(max(gx0    , 0), W - 1);
            int g1 = min(max(gx0 + 1, 0), W - 1);
            int g2 = min(max(gx0 + 2, 0), W - 1);
            int g3 = min(max(gx0 + 3, 0), W - 1);
            v0 = make_float4(ch0[rowb + g0], ch0[rowb + g1], ch0[rowb + g2], ch0[rowb + g3]);
            v1 = make_float4(ch1[rowb + g0], ch1[rowb + g1], ch1[rowb + g2], ch1[rowb + g3]);
            v2 = make_float4(ch2[rowb + g0], ch2[rowb + g1], ch2[rowb + g2], ch2[rowb + g3]);
        }
        Cell c0, c1, c2, c3;
        c0.a = __floats2half2_rn(v0.x, v1.x); c0.b = __floats2half2_rn(v2.x, 0.0f);
        c1.a = __floats2half2_rn(v0.y, v1.y); c1.b = __floats2half2_rn(v2.y, 0.0f);
        c2.a = __floats2half2_rn(v0.z, v1.z); c2.b = __floats2half2_rn(v2.z, 0.0f);
        c3.a = __floats2half2_rn(v0.w, v1.w); c3.b = __floats2half2_rn(v2.w, 0.0f);
        Cell2 q0; q0.c0 = c0; q0.c1 = c1;
        Cell2 q1; q1.c0 = c2; q1.c1 = c3;
        Cell2* dst = (Cell2*)&lds[r * STR + 4 * qc];   // 16B-aligned
        dst[0] = q0;
        dst[1] = q1;
    }
    __syncthreads();

    // ---- two pixels per thread, static unroll (registers only) ----
#pragma unroll
    for (int p = 0; p < 2; ++p) {
        const int y = Y + ty + p * 16;
        const int pos = y * W + x;
        const float fdx = fdxs[p];
        const float fdy = fdys[p];

        const float xm = (float)x + fdx;
        const float ym = (float)y + fdy;
        const float x0f = floorf(xm);
        const float y0f = floorf(ym);
        const float tfx = xm - x0f;
        const float tfy = ym - y0f;

        float cx[4], cy[4];
        cubic_coeffs(tfx, cx);
        cubic_coeffs(tfy, cy);

        const int x0 = (int)x0f;
        const int y0 = (int)y0f;

        float a0, a1, a2;

        // leftmost tap's LDS col = x0-1-(X-RTX) = x0-X+7; need [0, CLS-4]
        const unsigned ulx = (unsigned)(x0 - X + (RTX - 1));
        const unsigned uly = (unsigned)(y0 - Y + (RTY - 1));

        if (ulx <= (unsigned)(CLS - 4) && uly <= (unsigned)(RWS - 4)) {
            const Cell* __restrict__ base = lds + uly * STR + ulx;
            __half2 cxh[4], cyh[4];
#pragma unroll
            for (int j = 0; j < 4; ++j) {
                cxh[j] = __float2half2_rn(cx[j]);
                cyh[j] = __float2half2_rn(cy[j]);
            }
            __half2 acc01 = __float2half2_rn(0.0f);
            __half2 acc2  = __float2half2_rn(0.0f);
#pragma unroll
            for (int i = 0; i < 4; ++i) {
                const Cell* __restrict__ row = base + i * STR;
                Cell t0 = row[0];
                Cell t1 = row[1];
                Cell t2 = row[2];
                Cell t3 = row[3];
                __half2 r01 = __hmul2(cxh[0], t0.a);
                r01 = __hfma2(cxh[1], t1.a, r01);
                r01 = __hfma2(cxh[2], t2.a, r01);
                r01 = __hfma2(cxh[3], t3.a, r01);
                __half2 r2 = __hmul2(cxh[0], t0.b);
                r2 = __hfma2(cxh[1], t1.b, r2);
                r2 = __hfma2(cxh[2], t2.b, r2);
                r2 = __hfma2(cxh[3], t3.b, r2);
                acc01 = __hfma2(cyh[i], r01, acc01);
                acc2  = __hfma2(cyh[i], r2, acc2);
            }
            a0 = __low2float(acc01);
            a1 = __high2float(acc01);
            a2 = __low2float(acc2);
        } else {
            // rare tail (|delta| >= ~6): direct clamped f32 global gathers
            a0 = a1 = a2 = 0.0f;
            int xs[4], rowoff[4];
#pragma unroll
            for (int o = 0; o < 4; ++o) {
                xs[o] = min(max(x0 - 1 + o, 0), W - 1);
                rowoff[o] = min(max(y0 - 1 + o, 0), H - 1) * W;
            }
#pragma unroll
            for (int i = 0; i < 4; ++i) {
                float w0 = cy[i] * cx[0], w1 = cy[i] * cx[1];
                float w2 = cy[i] * cx[2], w3 = cy[i] * cx[3];
                const float* r0 = ch0 + rowoff[i];
                const float* r1 = ch1 + rowoff[i];
                const float* r2 = ch2 + rowoff[i];
                a0 = fmaf(w0, r0[xs[0]], a0); a0 = fmaf(w1, r0[xs[1]], a0);
                a0 = fmaf(w2, r0[xs[2]], a0); a0 = fmaf(w3, r0[xs[3]], a0);
                a1 = fmaf(w0, r1[xs[0]], a1); a1 = fmaf(w1, r1[xs[1]], a1);
                a1 = fmaf(w2, r1[xs[2]], a1); a1 = fmaf(w3, r1[xs[3]], a1);
                a2 = fmaf(w0, r2[xs[0]], a2); a2 = fmaf(w1, r2[xs[1]], a2);
                a2 = fmaf(w2, r2[xs[2]], a2); a2 = fmaf(w3, r2[xs[3]], a2);
            }
        }

        out[(size_t)db * hw + pos] = a0;
        out[(size_t)(db + B) * hw + pos] = a1;
        out[(size_t)(db + 2 * B) * hw + pos] = a2;
    }
}

extern "C" void kernel_launch(void* const* d_in, const int* in_sizes, int n_in,
                              void* d_out, int out_size, void* d_ws, size_t ws_size,
                              hipStream_t stream) {
    const float* img = (const float*)d_in[0];
    const float* dx  = (const float*)d_in[1];
    const float* dy  = (const float*)d_in[2];
    float* out = (float*)d_out;

    const int B = 8, C = 3, H = 1024, W = 1024;
    dim3 block(64, 16, 1);
    dim3 grid(W / 64, H / 32, B);
    warp_bicubic_kernel<<<grid, block, 0, stream>>>(img, dx, dy, out, B, C, H, W);
}

// Round 15
// 63.978 us; speedup vs baseline: 2.2399x; 1.0946x over previous
//
#include <hip/hip_runtime.h>
#include <hip/hip_fp16.h>

// Bicubic (Catmull-Rom) warp, faithful to the reference's tile/reshape quirk:
// output plane k uses IMAGE plane k warped with DELTA plane (k % B).
//
// FINAL (= round-9, best measured: 63.3 us wall). 64x16 tile / 1024 threads,
// 30x80-cell fp16 channel-packed halo (one ds_read_b64 per tap), quad-
// vectorized staging, factorized packed-half accumulation, per-pixel delta
// loads issued at the TOP of the kernel (latency hides under staging +
// barrier wait; the compiler cannot hoist them across __syncthreads).
//
// Explored and refuted from this base:
//  - LDS stride/layout changes (r5/r6): conflicts are the irreducible
//    balls-in-bins imbalance of jittered lane addresses, ~1.38e7 cyc/disp.
//  - b32 read-width split (r13): +8 reads/px cost more than conflicts saved.
//  - Register-staged pipelined strips (r10-12): compiler demotes in-flight
//    staging regs to scratch (+64..126 MB HBM), unviable at HIP source.
//  - 64x32 tile, 2 px/thread (r14): longer dep chain, fewer blocks -> -10%.
// At wall speed the LDS read pipe is ~72% of cycles and saturated-ish;
// VALU ~47%, HBM ~58% -- this is the algorithm's floor in this form.
//
// Coordinates: xm = x + dx directly (the reference's normalize->unnormalize
// roundtrip is an algebraic identity; fp deviation ~1e-4 px vs 0.1 abs
// threshold). Halo covers |delta| < ~6 (P ~ 2e-9/px); per-lane clamped f32
// global fallback otherwise.

#define RTY 7      // top margin (rows above Y)
#define RWS 30     // halo rows
#define RTX 8      // left margin (cols left of X)
#define CLS 80     // halo cols (20 quads)
#define STR 82     // LDS row stride in cells (656 B, 16B-multiple)
#define NQ  (RWS * (CLS / 4))   // 600 staging quads

struct alignas(8) Cell {
    __half2 a;   // (ch0, ch1)
    __half2 b;   // (ch2, 0)
};
struct alignas(16) Cell2 { Cell c0, c1; };

__device__ __forceinline__ void cubic_coeffs(float t, float c[4]) {
    float t2 = t * t;
    float t3 = t2 * t;
    c[0] = (-t3 + 2.0f * t2 - t) * 0.5f;
    c[1] = (3.0f * t3 - 5.0f * t2 + 2.0f) * 0.5f;
    c[2] = (-3.0f * t3 + 4.0f * t2 + t) * 0.5f;
    c[3] = 1.0f - (c[0] + c[1] + c[2]);
}

__global__ __launch_bounds__(1024, 8) void warp_bicubic_kernel(
    const float* __restrict__ img,
    const float* __restrict__ dx,
    const float* __restrict__ dy,
    float* __restrict__ out,
    int B, int C, int H, int W)
{
    __shared__ Cell lds[RWS * STR];   // 19680 B -> 2 blocks/CU, 32 waves

    const int tx = threadIdx.x;              // 0..63
    const int ty = threadIdx.y;              // 0..15
    const int tid = ty * 64 + tx;
    const int X = blockIdx.x * 64;
    const int Y = blockIdx.y * 16;
    const int db = blockIdx.z;
    const int hw = H * W;

    // ---- issue per-pixel delta loads FIRST: latency hides under staging ----
    const int x = X + tx;
    const int y = Y + ty;
    const int pos  = y * W + x;
    const int dofs = db * hw + pos;
    const float fdx = dx[dofs];
    const float fdy = dy[dofs];

    const float* __restrict__ ch0 = img + (size_t)db * hw;
    const float* __restrict__ ch1 = img + (size_t)(db + B) * hw;
    const float* __restrict__ ch2 = img + (size_t)(db + 2 * B) * hw;

    // ---- stage halo: one 4-cell quad per thread (tid < 600) ----
    if (tid < NQ) {
        int r  = tid / 20;                   // halo row
        int qc = tid - r * 20;               // quad col
        int gy  = Y - RTY + r;
        int gx0 = X - RTX + 4 * qc;          // 16B-aligned when in-bounds
        Cell cells[4];
        if (gy >= 0 && gy < H && gx0 >= 0 && gx0 <= W - 4) {
            size_t off = (size_t)gy * W + gx0;
            float4 v0 = *(const float4*)(ch0 + off);
            float4 v1 = *(const float4*)(ch1 + off);
            float4 v2 = *(const float4*)(ch2 + off);
            cells[0].a = __floats2half2_rn(v0.x, v1.x);
            cells[0].b = __floats2half2_rn(v2.x, 0.0f);
            cells[1].a = __floats2half2_rn(v0.y, v1.y);
            cells[1].b = __floats2half2_rn(v2.y, 0.0f);
            cells[2].a = __floats2half2_rn(v0.z, v1.z);
            cells[2].b = __floats2half2_rn(v2.z, 0.0f);
            cells[3].a = __floats2half2_rn(v0.w, v1.w);
            cells[3].b = __floats2half2_rn(v2.w, 0.0f);
        } else {
            int gyc = min(max(gy, 0), H - 1);
#pragma unroll
            for (int e = 0; e < 4; ++e) {
                int gxc = min(max(gx0 + e, 0), W - 1);
                size_t off = (size_t)gyc * W + gxc;
                cells[e].a = __floats2half2_rn(ch0[off], ch1[off]);
                cells[e].b = __floats2half2_rn(ch2[off], 0.0f);
            }
        }
        Cell2* dst = (Cell2*)&lds[r * STR + 4 * qc];   // 16B-aligned
        dst[0] = *(const Cell2*)&cells[0];
        dst[1] = *(const Cell2*)&cells[2];
    }
    __syncthreads();

    // ---- per-pixel coords & weights (delta already in registers) ----
    const float xm = (float)x + fdx;
    const float ym = (float)y + fdy;
    const float x0f = floorf(xm);
    const float y0f = floorf(ym);
    const float tfx = xm - x0f;
    const float tfy = ym - y0f;

    float cx[4], cy[4];
    cubic_coeffs(tfx, cx);
    cubic_coeffs(tfy, cy);

    const int x0 = (int)x0f;
    const int y0 = (int)y0f;

    float a0, a1, a2;

    // leftmost tap col in LDS = x0-1-(X-RTX) = x0-X+7; need [0, CLS-4]
    const unsigned ulx = (unsigned)(x0 - X + (RTX - 1));
    const unsigned uly = (unsigned)(y0 - Y + (RTY - 1));

    if (ulx <= (unsigned)(CLS - 4) && uly <= (unsigned)(RWS - 4)) {
        const Cell* __restrict__ base = lds + uly * STR + ulx;
        __half2 cxh[4], cyh[4];
#pragma unroll
        for (int j = 0; j < 4; ++j) {
            cxh[j] = __float2half2_rn(cx[j]);
            cyh[j] = __float2half2_rn(cy[j]);
        }
        __half2 acc01 = __float2half2_rn(0.0f);
        __half2 acc2  = __float2half2_rn(0.0f);
#pragma unroll
        for (int i = 0; i < 4; ++i) {
            const Cell* __restrict__ row = base + i * STR;
            Cell t0 = row[0];
            Cell t1 = row[1];
            Cell t2 = row[2];
            Cell t3 = row[3];
            __half2 r01 = __hmul2(cxh[0], t0.a);
            r01 = __hfma2(cxh[1], t1.a, r01);
            r01 = __hfma2(cxh[2], t2.a, r01);
            r01 = __hfma2(cxh[3], t3.a, r01);
            __half2 r2 = __hmul2(cxh[0], t0.b);
            r2 = __hfma2(cxh[1], t1.b, r2);
            r2 = __hfma2(cxh[2], t2.b, r2);
            r2 = __hfma2(cxh[3], t3.b, r2);
            acc01 = __hfma2(cyh[i], r01, acc01);
            acc2  = __hfma2(cyh[i], r2, acc2);
        }
        a0 = __low2float(acc01);
        a1 = __high2float(acc01);
        a2 = __low2float(acc2);
    } else {
        // rare tail (|delta| >= ~6): direct clamped f32 global gathers
        a0 = a1 = a2 = 0.0f;
        int xs[4], rowoff[4];
#pragma unroll
        for (int o = 0; o < 4; ++o) {
            xs[o] = min(max(x0 - 1 + o, 0), W - 1);
            rowoff[o] = min(max(y0 - 1 + o, 0), H - 1) * W;
        }
#pragma unroll
        for (int i = 0; i < 4; ++i) {
            float w0 = cy[i] * cx[0], w1 = cy[i] * cx[1];
            float w2 = cy[i] * cx[2], w3 = cy[i] * cx[3];
            const float* r0 = ch0 + rowoff[i];
            const float* r1 = ch1 + rowoff[i];
            const float* r2 = ch2 + rowoff[i];
            a0 = fmaf(w0, r0[xs[0]], a0); a0 = fmaf(w1, r0[xs[1]], a0);
            a0 = fmaf(w2, r0[xs[2]], a0); a0 = fmaf(w3, r0[xs[3]], a0);
            a1 = fmaf(w0, r1[xs[0]], a1); a1 = fmaf(w1, r1[xs[1]], a1);
            a1 = fmaf(w2, r1[xs[2]], a1); a1 = fmaf(w3, r1[xs[3]], a1);
            a2 = fmaf(w0, r2[xs[0]], a2); a2 = fmaf(w1, r2[xs[1]], a2);
            a2 = fmaf(w2, r2[xs[2]], a2); a2 = fmaf(w3, r2[xs[3]], a2);
        }
    }

    out[(size_t)db * hw + pos] = a0;
    out[(size_t)(db + B) * hw + pos] = a1;
    out[(size_t)(db + 2 * B) * hw + pos] = a2;
}

extern "C" void kernel_launch(void* const* d_in, const int* in_sizes, int n_in,
                              void* d_out, int out_size, void* d_ws, size_t ws_size,
                              hipStream_t stream) {
    const float* img = (const float*)d_in[0];
    const float* dx  = (const float*)d_in[1];
    const float* dy  = (const float*)d_in[2];
    float* out = (float*)d_out;

    const int B = 8, C = 3, H = 1024, W = 1024;
    dim3 block(64, 16, 1);
    dim3 grid(W / 64, H / 16, B);
    warp_bicubic_kernel<<<grid, block, 0, stream>>>(img, dx, dy, out, B, C, H, W);
}